// Round 12
// baseline (44.112 us; speedup 1.0000x reference)
//
#include <hip/hip_runtime.h>
#include <cmath>

// RMSDLoss (batched Kabsch RMSD, mean over batch).
// R6/R9 plateau at 26.6us with stride-96 lane layout: each wave load touches
// ~80-96 cache lines (64 lanes x 16B over a 6KB span) -> L1 line-transaction
// amplification ~5x vs contiguous. R12: lane-contiguous dwordx3 atom loads —
// round k reads atom (k*256+tid), wave instr = 768B CONTIGUOUS (12 lines).
// Every thread still holds whole atoms of p AND q (cross-terms need that;
// sums don't care about atom order). Burst structure from R9 (proven):
// 2 phases x 8 loads + sched_barrier(0), __launch_bounds__(256,8).
// fp32 solve (absmax 0.0 across R2-R11), separate mean kernel (fusion
// attempts R3/R5/R10 all regressed).

constexpr int BLOCK = 256;
constexpr int NWAVE = BLOCK / 64;
constexpr int NS = 17;

struct atom3 { float x, y, z; };   // 12B -> global_load_dwordx3

template<int N>
__global__ __launch_bounds__(BLOCK, 8) void rmsd_kernel(
    const float* __restrict__ yp,   // [B,N,3] coords (y_prime)
    const float* __restrict__ yr,   // [B,N,3] reference (y)
    float* __restrict__ rms_out)    // [B]
{
    static_assert(N == BLOCK * 8, "8 atoms per thread");
    const int b   = blockIdx.x;
    const int tid = threadIdx.x;
    const size_t row = (size_t)b * (size_t)N * 3u;
    const atom3* p3 = (const atom3*)(yp + row);
    const atom3* q3 = (const atom3*)(yr + row);

    float s1x=0.f,s1y=0.f,s1z=0.f, s2x=0.f,s2y=0.f,s2z=0.f, sq1=0.f,sq2=0.f;
    float c00=0.f,c01=0.f,c02=0.f,c10=0.f,c11=0.f,c12=0.f,c20=0.f,c21=0.f,c22=0.f;

    auto accum1 = [&](const atom3& P, const atom3& Q){
        s1x += P.x; s1y += P.y; s1z += P.z;
        s2x += Q.x; s2y += Q.y; s2z += Q.z;
        sq1 = fmaf(P.x,P.x, fmaf(P.y,P.y, fmaf(P.z,P.z, sq1)));
        sq2 = fmaf(Q.x,Q.x, fmaf(Q.y,Q.y, fmaf(Q.z,Q.z, sq2)));
        c00 = fmaf(P.x,Q.x,c00); c01 = fmaf(P.x,Q.y,c01); c02 = fmaf(P.x,Q.z,c02);
        c10 = fmaf(P.y,Q.x,c10); c11 = fmaf(P.y,Q.y,c11); c12 = fmaf(P.y,Q.z,c12);
        c20 = fmaf(P.z,Q.x,c20); c21 = fmaf(P.z,Q.y,c21); c22 = fmaf(P.z,Q.z,c22);
    };

    // Phase A: rounds 0..3 — each load: 64 consecutive atoms = 768B contiguous.
    {
        const atom3 P0 = p3[0*BLOCK + tid], P1 = p3[1*BLOCK + tid];
        const atom3 P2 = p3[2*BLOCK + tid], P3 = p3[3*BLOCK + tid];
        const atom3 Q0 = q3[0*BLOCK + tid], Q1 = q3[1*BLOCK + tid];
        const atom3 Q2 = q3[2*BLOCK + tid], Q3 = q3[3*BLOCK + tid];
        __builtin_amdgcn_sched_barrier(0);   // all 8 loads issued before consume
        accum1(P0,Q0); accum1(P1,Q1); accum1(P2,Q2); accum1(P3,Q3);
    }
    // Phase B: rounds 4..7.
    {
        const atom3 P4 = p3[4*BLOCK + tid], P5 = p3[5*BLOCK + tid];
        const atom3 P6 = p3[6*BLOCK + tid], P7 = p3[7*BLOCK + tid];
        const atom3 Q4 = q3[4*BLOCK + tid], Q5 = q3[5*BLOCK + tid];
        const atom3 Q6 = q3[6*BLOCK + tid], Q7 = q3[7*BLOCK + tid];
        __builtin_amdgcn_sched_barrier(0);
        accum1(P4,Q4); accum1(P5,Q5); accum1(P6,Q6); accum1(P7,Q7);
    }

    // Block reduction of the 17 sums.
    float vals[NS] = {s1x,s1y,s1z,s2x,s2y,s2z,sq1,sq2,
                      c00,c01,c02,c10,c11,c12,c20,c21,c22};
    __shared__ float sred[NWAVE][NS];
    const int wave = tid >> 6, lane = tid & 63;
    #pragma unroll
    for (int i = 0; i < NS; ++i) {
        float v = vals[i];
        #pragma unroll
        for (int off = 32; off > 0; off >>= 1) v += __shfl_down(v, off, 64);
        if (lane == 0) sred[wave][i] = v;
    }
    __syncthreads();

    if (tid == 0) {
        float t[NS];
        #pragma unroll
        for (int i = 0; i < NS; ++i) {
            float s = 0.f;
            #pragma unroll
            for (int w = 0; w < NWAVE; ++w) s += sred[w][i];
            t[i] = s;
        }
        const float fn = (float)N;
        const float m1x=t[0]/fn, m1y=t[1]/fn, m1z=t[2]/fn;
        const float m2x=t[3]/fn, m2y=t[4]/fn, m2z=t[5]/fn;
        const float E0 = (t[6] - fn*(m1x*m1x+m1y*m1y+m1z*m1z))
                       + (t[7] - fn*(m2x*m2x+m2y*m2y+m2z*m2z));
        const float A00=t[8] -fn*m1x*m2x, A01=t[9] -fn*m1x*m2y, A02=t[10]-fn*m1x*m2z;
        const float A10=t[11]-fn*m1y*m2x, A11=t[12]-fn*m1y*m2y, A12=t[13]-fn*m1y*m2z;
        const float A20=t[14]-fn*m1z*m2x, A21=t[15]-fn*m1z*m2y, A22=t[16]-fn*m1z*m2z;

        const float det = A00*(A11*A22-A12*A21)
                        - A01*(A10*A22-A12*A20)
                        + A02*(A10*A21-A11*A20);

        // G = A^T A (symmetric PSD); analytic eigenvalues (fp32)
        const float G00 = A00*A00+A10*A10+A20*A20;
        const float G01 = A00*A01+A10*A11+A20*A21;
        const float G02 = A00*A02+A10*A12+A20*A22;
        const float G11 = A01*A01+A11*A11+A21*A21;
        const float G12 = A01*A02+A11*A12+A21*A22;
        const float G22 = A02*A02+A12*A12+A22*A22;

        const float q  = (G00+G11+G22)*(1.f/3.f);
        const float p1 = G01*G01 + G02*G02 + G12*G12;
        const float p2 = (G00-q)*(G00-q)+(G11-q)*(G11-q)+(G22-q)*(G22-q) + 2.f*p1;
        const float p  = sqrtf(p2*(1.f/6.f));
        float e1, e2, e3;
        if (p < 1e-20f) {
            e1 = e2 = e3 = q;
        } else {
            const float ip = 1.f/p;
            const float C00=(G00-q)*ip, C01=G01*ip, C02=G02*ip;
            const float C11=(G11-q)*ip, C12=G12*ip, C22=(G22-q)*ip;
            float detC = C00*(C11*C22-C12*C12)
                       - C01*(C01*C22-C12*C02)
                       + C02*(C01*C12-C11*C02);
            float rr = fminf(1.f, fmaxf(-1.f, 0.5f*detC));
            const float phi = acosf(rr)*(1.f/3.f);
            e1 = q + 2.f*p*cosf(phi);
            e3 = q + 2.f*p*cosf(phi + 2.0943951023931953f);  // +2*pi/3
            e2 = 3.f*q - e1 - e3;
        }
        const float sv0 = sqrtf(fmaxf(e1,0.f));
        const float sv1 = sqrtf(fmaxf(e2,0.f));
        const float sv2 = sqrtf(fmaxf(e3,0.f));
        const float trs = sv0 + sv1 + ((det >= 0.f) ? sv2 : -sv2);
        const float msd = fmaxf(0.f, (E0 - 2.f*trs)/fn);
        rms_out[b] = sqrtf(msd);
    }
}

__global__ __launch_bounds__(BLOCK) void mean_kernel(
    const float* __restrict__ rms, float* __restrict__ out, int B)
{
    const int tid = threadIdx.x;
    const float4* r4 = (const float4*)rms;
    float s = 0.f;
    for (int i = tid; i < B/4; i += BLOCK) {
        float4 v = r4[i];
        s += (v.x + v.y) + (v.z + v.w);
    }
    #pragma unroll
    for (int off = 32; off > 0; off >>= 1) s += __shfl_down(s, off, 64);
    __shared__ float sred[NWAVE];
    const int wave = tid >> 6, lane = tid & 63;
    if (lane == 0) sred[wave] = s;
    __syncthreads();
    if (tid == 0) {
        float tot = 0.f;
        #pragma unroll
        for (int w = 0; w < NWAVE; ++w) tot += sred[w];
        out[0] = tot / (float)B;
    }
}

extern "C" void kernel_launch(void* const* d_in, const int* in_sizes, int n_in,
                              void* d_out, int out_size, void* d_ws, size_t ws_size,
                              hipStream_t stream) {
    const float* yp = (const float*)d_in[0];   // y_prime [B,N,3] f32
    const float* yr = (const float*)d_in[1];   // y       [B,N,3] f32
    const int N = 2048;
    const int B = in_sizes[0] / (N * 3);
    float* rms_ws = (float*)d_ws;              // B floats

    rmsd_kernel<2048><<<B, BLOCK, 0, stream>>>(yp, yr, rms_ws);
    mean_kernel<<<1, BLOCK, 0, stream>>>(rms_ws, (float*)d_out, B);
}

// Round 13
// 28.881 us; speedup vs baseline: 1.5274x; 1.5274x over previous
//
#include <hip/hip_runtime.h>
#include <cmath>
#include <cstdint>

// RMSDLoss (batched Kabsch RMSD, mean over batch).
// R6/R9 plateau (26.6us): stride-96 lane layout -> ~80 L1 line-transactions
// per wave load (5x amplification) ~= 13us of line servicing. R4/R12 fixes
// via VGPR staging were destroyed by regalloc (VGPR=32 + 24MB scratch spill).
// R13: global_load_lds staging — lane-contiguous 1KB/wave-instr (16 lines),
// ZERO data VGPRs, can't be spilled. LDS consume at 12B/atom (stride-3 words,
// gcd(3,32)=1 -> conflict-free). Double-buffered 512-atom chunks, counted
// vmcnt + raw s_barrier (NOT __syncthreads -> would drain prefetch, R3 bug).
// fp32 solve (absmax 0.0 across R2-R12), separate mean kernel (fusion lost
// 3x: R3/R5/R10).

constexpr int BLOCK = 256;
constexpr int NWAVE = BLOCK / 64;
constexpr int NS = 17;
constexpr int CHUNK_ATOMS = 512;
constexpr int CHUNK_BYTES = CHUNK_ATOMS * 12;        // 6144 per tensor
constexpr int CHUNK_F = CHUNK_ATOMS * 3;             // 1536 floats per tensor

__device__ __forceinline__ void gload_lds16(const void* g, void* l) {
    __builtin_amdgcn_global_load_lds(
        (const __attribute__((address_space(1))) void*)(uintptr_t)g,
        (__attribute__((address_space(3))) void*)(uintptr_t)l,
        16, 0, 0);
}

template<int N>
__global__ __launch_bounds__(BLOCK, 6) void rmsd_kernel(
    const float* __restrict__ yp,   // [B,N,3] coords (y_prime)
    const float* __restrict__ yr,   // [B,N,3] reference (y)
    float* __restrict__ rms_out)    // [B]
{
    __shared__ float ldsP[2][CHUNK_F];   // 2 x 6KB
    __shared__ float ldsQ[2][CHUNK_F];   // 2 x 6KB   -> 24KB total
    __shared__ float sred[NWAVE][NS];

    const int b    = blockIdx.x;
    const int tid  = threadIdx.x;
    const int wave = tid >> 6, lane = tid & 63;
    const char* pbase = (const char*)(yp + (size_t)b * N * 3);
    const char* qbase = (const char*)(yr + (size_t)b * N * 3);
    constexpr int NCHUNK = N / CHUNK_ATOMS;          // 4

    // Stage chunk c into buffer buf: 12 x 1KB wave-instrs; wave w issues
    // k = 3w..3w+2; k<6 -> P, else Q. LDS dest is wave-uniform; HW adds
    // lane*16. Global src is lane-contiguous (16B/lane).
    auto stage = [&](int c, int buf){
        const int k0 = wave * 3;
        #pragma unroll
        for (int j = 0; j < 3; ++j) {
            const int k  = k0 + j;
            const int t  = k / 6;
            const int iw = k % 6;
            const char* g = (t ? qbase : pbase)
                          + (size_t)c * CHUNK_BYTES + iw * 1024 + lane * 16;
            char* l = (char*)(t ? &ldsQ[buf][0] : &ldsP[buf][0]) + iw * 1024;
            gload_lds16(g, l);
        }
    };

    float s1x=0.f,s1y=0.f,s1z=0.f, s2x=0.f,s2y=0.f,s2z=0.f, sq1=0.f,sq2=0.f;
    float c00=0.f,c01=0.f,c02=0.f,c10=0.f,c11=0.f,c12=0.f,c20=0.f,c21=0.f,c22=0.f;

    auto accum1 = [&](float px, float py, float pz, float qx, float qy, float qz){
        s1x += px; s1y += py; s1z += pz;
        s2x += qx; s2y += qy; s2z += qz;
        sq1 = fmaf(px,px, fmaf(py,py, fmaf(pz,pz, sq1)));
        sq2 = fmaf(qx,qx, fmaf(qy,qy, fmaf(qz,qz, sq2)));
        c00 = fmaf(px,qx,c00); c01 = fmaf(px,qy,c01); c02 = fmaf(px,qz,c02);
        c10 = fmaf(py,qx,c10); c11 = fmaf(py,qy,c11); c12 = fmaf(py,qz,c12);
        c20 = fmaf(pz,qx,c20); c21 = fmaf(pz,qy,c21); c22 = fmaf(pz,qz,c22);
    };

    stage(0, 0);

    for (int c = 0; c < NCHUNK; ++c) {
        const int buf = c & 1;
        if (c + 1 < NCHUNK) {
            stage(c + 1, buf ^ 1);
            // Own stage(c) (3 oldest) drained; stage(c+1)'s 3 stay in flight.
            asm volatile("s_waitcnt vmcnt(3)" ::: "memory");
        } else {
            asm volatile("s_waitcnt vmcnt(0)" ::: "memory");
        }
        __builtin_amdgcn_s_barrier();        // all waves' stage(c) complete
        asm volatile("" ::: "memory");

        // Consume: atoms tid and tid+256 of the chunk (stride-3 words,
        // conflict-free). Values land in regs before the trailing barrier.
        {
            const float* lp = &ldsP[buf][0];
            const float* lq = &ldsQ[buf][0];
            const int a0 = 3 * tid;
            const int a1 = 3 * (tid + 256);
            accum1(lp[a0], lp[a0+1], lp[a0+2], lq[a0], lq[a0+1], lq[a0+2]);
            accum1(lp[a1], lp[a1+1], lp[a1+2], lq[a1], lq[a1+1], lq[a1+2]);
        }
        asm volatile("" ::: "memory");
        __builtin_amdgcn_s_barrier();        // all consumed before overwrite
    }

    // Block reduction of the 17 sums.
    float vals[NS] = {s1x,s1y,s1z,s2x,s2y,s2z,sq1,sq2,
                      c00,c01,c02,c10,c11,c12,c20,c21,c22};
    #pragma unroll
    for (int i = 0; i < NS; ++i) {
        float v = vals[i];
        #pragma unroll
        for (int off = 32; off > 0; off >>= 1) v += __shfl_down(v, off, 64);
        if (lane == 0) sred[wave][i] = v;
    }
    __syncthreads();

    if (tid == 0) {
        float t[NS];
        #pragma unroll
        for (int i = 0; i < NS; ++i) {
            float s = 0.f;
            #pragma unroll
            for (int w = 0; w < NWAVE; ++w) s += sred[w][i];
            t[i] = s;
        }
        const float fn = (float)N;
        const float m1x=t[0]/fn, m1y=t[1]/fn, m1z=t[2]/fn;
        const float m2x=t[3]/fn, m2y=t[4]/fn, m2z=t[5]/fn;
        const float E0 = (t[6] - fn*(m1x*m1x+m1y*m1y+m1z*m1z))
                       + (t[7] - fn*(m2x*m2x+m2y*m2y+m2z*m2z));
        const float A00=t[8] -fn*m1x*m2x, A01=t[9] -fn*m1x*m2y, A02=t[10]-fn*m1x*m2z;
        const float A10=t[11]-fn*m1y*m2x, A11=t[12]-fn*m1y*m2y, A12=t[13]-fn*m1y*m2z;
        const float A20=t[14]-fn*m1z*m2x, A21=t[15]-fn*m1z*m2y, A22=t[16]-fn*m1z*m2z;

        const float det = A00*(A11*A22-A12*A21)
                        - A01*(A10*A22-A12*A20)
                        + A02*(A10*A21-A11*A20);

        // G = A^T A (symmetric PSD); analytic eigenvalues (fp32)
        const float G00 = A00*A00+A10*A10+A20*A20;
        const float G01 = A00*A01+A10*A11+A20*A21;
        const float G02 = A00*A02+A10*A12+A20*A22;
        const float G11 = A01*A01+A11*A11+A21*A21;
        const float G12 = A01*A02+A11*A12+A21*A22;
        const float G22 = A02*A02+A12*A12+A22*A22;

        const float q  = (G00+G11+G22)*(1.f/3.f);
        const float p1 = G01*G01 + G02*G02 + G12*G12;
        const float p2 = (G00-q)*(G00-q)+(G11-q)*(G11-q)+(G22-q)*(G22-q) + 2.f*p1;
        const float p  = sqrtf(p2*(1.f/6.f));
        float e1, e2, e3;
        if (p < 1e-20f) {
            e1 = e2 = e3 = q;
        } else {
            const float ip = 1.f/p;
            const float C00=(G00-q)*ip, C01=G01*ip, C02=G02*ip;
            const float C11=(G11-q)*ip, C12=G12*ip, C22=(G22-q)*ip;
            float detC = C00*(C11*C22-C12*C12)
                       - C01*(C01*C22-C12*C02)
                       + C02*(C01*C12-C11*C02);
            float rr = fminf(1.f, fmaxf(-1.f, 0.5f*detC));
            const float phi = acosf(rr)*(1.f/3.f);
            e1 = q + 2.f*p*cosf(phi);
            e3 = q + 2.f*p*cosf(phi + 2.0943951023931953f);  // +2*pi/3
            e2 = 3.f*q - e1 - e3;
        }
        const float sv0 = sqrtf(fmaxf(e1,0.f));
        const float sv1 = sqrtf(fmaxf(e2,0.f));
        const float sv2 = sqrtf(fmaxf(e3,0.f));
        const float trs = sv0 + sv1 + ((det >= 0.f) ? sv2 : -sv2);
        const float msd = fmaxf(0.f, (E0 - 2.f*trs)/fn);
        rms_out[b] = sqrtf(msd);
    }
}

__global__ __launch_bounds__(BLOCK) void mean_kernel(
    const float* __restrict__ rms, float* __restrict__ out, int B)
{
    const int tid = threadIdx.x;
    const float4* r4 = (const float4*)rms;
    float s = 0.f;
    for (int i = tid; i < B/4; i += BLOCK) {
        float4 v = r4[i];
        s += (v.x + v.y) + (v.z + v.w);
    }
    #pragma unroll
    for (int off = 32; off > 0; off >>= 1) s += __shfl_down(s, off, 64);
    __shared__ float sred[NWAVE];
    const int wave = tid >> 6, lane = tid & 63;
    if (lane == 0) sred[wave] = s;
    __syncthreads();
    if (tid == 0) {
        float tot = 0.f;
        #pragma unroll
        for (int w = 0; w < NWAVE; ++w) tot += sred[w];
        out[0] = tot / (float)B;
    }
}

extern "C" void kernel_launch(void* const* d_in, const int* in_sizes, int n_in,
                              void* d_out, int out_size, void* d_ws, size_t ws_size,
                              hipStream_t stream) {
    const float* yp = (const float*)d_in[0];   // y_prime [B,N,3] f32
    const float* yr = (const float*)d_in[1];   // y       [B,N,3] f32
    const int N = 2048;
    const int B = in_sizes[0] / (N * 3);
    float* rms_ws = (float*)d_ws;              // B floats

    rmsd_kernel<2048><<<B, BLOCK, 0, stream>>>(yp, yr, rms_ws);
    mean_kernel<<<1, BLOCK, 0, stream>>>(rms_ws, (float*)d_out, B);
}

// Round 14
// 27.020 us; speedup vs baseline: 1.6326x; 1.0689x over previous
//
#include <hip/hip_runtime.h>
#include <cmath>

// RMSDLoss (batched Kabsch RMSD, mean over batch) — FINAL (R9 configuration,
// the session best at 26.6us, resubmitted to lock in).
//
// Evidence this is the practical roofline:
//  - R6 (12-load burst, 6 blk/CU) == R9 (2x6 burst, 8 blk/CU) == 26.6us, and
//    R13 (global_load_lds staging, lane-contiguous, counted vmcnt) = 28.9us:
//    three structurally different designs converge -> memory pipe saturated,
//    line-utilization and per-wave MLP are not the limiter.
//  - Effective read service ~4.6 TB/s (the 6.29 TB/s ubench is a COPY;
//    write-only fill does 6.9 TB/s; pure-read rate here measures ~4.6-4.8).
//    100.66 MB / ~4.7 TB/s ~= 21.5us main kernel == measured.
//  - Mean fusion is architecture-blocked (cross-XCD L2 non-coherence):
//    R3/R5 same-address atomics +15-20us; R10 per-block threadfence 3x
//    slowdown. Separate 1-block mean kernel (+~4us) is the cheapest legal way.
//  - No slack in counters: 0 bank conflicts, VALUBusy ~11%, no spills.

constexpr int BLOCK = 256;
constexpr int NWAVE = BLOCK / 64;
constexpr int NS = 17;

template<int N>
__global__ __launch_bounds__(BLOCK, 8) void rmsd_kernel(
    const float* __restrict__ yp,   // [B,N,3] coords (y_prime)
    const float* __restrict__ yr,   // [B,N,3] reference (y)
    float* __restrict__ rms_out)    // [B]
{
    static_assert(N == BLOCK * 8, "one thread = 8 atoms = 6 float4");
    const int b   = blockIdx.x;
    const int tid = threadIdx.x;
    const size_t row = (size_t)b * (size_t)N * 3u;
    const float4* p4 = (const float4*)(yp + row) + tid * 6;
    const float4* q4 = (const float4*)(yr + row) + tid * 6;

    float s1x=0.f,s1y=0.f,s1z=0.f, s2x=0.f,s2y=0.f,s2z=0.f, sq1=0.f,sq2=0.f;
    float c00=0.f,c01=0.f,c02=0.f,c10=0.f,c11=0.f,c12=0.f,c20=0.f,c21=0.f,c22=0.f;

    auto accum4 = [&](const float4&a0,const float4&a1,const float4&a2,
                      const float4&b0,const float4&b1,const float4&b2){
        float px[4]={a0.x,a0.w,a1.z,a2.y};
        float py[4]={a0.y,a1.x,a1.w,a2.z};
        float pz[4]={a0.z,a1.y,a2.x,a2.w};
        float qx[4]={b0.x,b0.w,b1.z,b2.y};
        float qy[4]={b0.y,b1.x,b1.w,b2.z};
        float qz[4]={b0.z,b1.y,b2.x,b2.w};
        #pragma unroll
        for (int k=0;k<4;k++){
            s1x+=px[k]; s1y+=py[k]; s1z+=pz[k];
            s2x+=qx[k]; s2y+=qy[k]; s2z+=qz[k];
            sq1 = fmaf(px[k],px[k], fmaf(py[k],py[k], fmaf(pz[k],pz[k], sq1)));
            sq2 = fmaf(qx[k],qx[k], fmaf(qy[k],qy[k], fmaf(qz[k],qz[k], sq2)));
            c00=fmaf(px[k],qx[k],c00); c01=fmaf(px[k],qy[k],c01); c02=fmaf(px[k],qz[k],c02);
            c10=fmaf(py[k],qx[k],c10); c11=fmaf(py[k],qy[k],c11); c12=fmaf(py[k],qz[k],c12);
            c20=fmaf(pz[k],qx[k],c20); c21=fmaf(pz[k],qy[k],c21); c22=fmaf(pz[k],qz[k],c22);
        }
    };

    // Phase A: 6-load burst (atoms 0..3), issue all before consuming.
    {
        const float4 P0=p4[0], P1=p4[1], P2=p4[2];
        const float4 Q0=q4[0], Q1=q4[1], Q2=q4[2];
        __builtin_amdgcn_sched_barrier(0);
        accum4(P0,P1,P2, Q0,Q1,Q2);
    }
    // Phase B: 6-load burst (atoms 4..7).
    {
        const float4 P3=p4[3], P4=p4[4], P5=p4[5];
        const float4 Q3=q4[3], Q4=q4[4], Q5=q4[5];
        __builtin_amdgcn_sched_barrier(0);
        accum4(P3,P4,P5, Q3,Q4,Q5);
    }

    // Block reduction of the 17 sums.
    float vals[NS] = {s1x,s1y,s1z,s2x,s2y,s2z,sq1,sq2,
                      c00,c01,c02,c10,c11,c12,c20,c21,c22};
    __shared__ float sred[NWAVE][NS];
    const int wave = tid >> 6, lane = tid & 63;
    #pragma unroll
    for (int i = 0; i < NS; ++i) {
        float v = vals[i];
        #pragma unroll
        for (int off = 32; off > 0; off >>= 1) v += __shfl_down(v, off, 64);
        if (lane == 0) sred[wave][i] = v;
    }
    __syncthreads();

    if (tid == 0) {
        float t[NS];
        #pragma unroll
        for (int i = 0; i < NS; ++i) {
            float s = 0.f;
            #pragma unroll
            for (int w = 0; w < NWAVE; ++w) s += sred[w][i];
            t[i] = s;
        }
        const float fn = (float)N;
        const float m1x=t[0]/fn, m1y=t[1]/fn, m1z=t[2]/fn;
        const float m2x=t[3]/fn, m2y=t[4]/fn, m2z=t[5]/fn;
        const float E0 = (t[6] - fn*(m1x*m1x+m1y*m1y+m1z*m1z))
                       + (t[7] - fn*(m2x*m2x+m2y*m2y+m2z*m2z));
        const float A00=t[8] -fn*m1x*m2x, A01=t[9] -fn*m1x*m2y, A02=t[10]-fn*m1x*m2z;
        const float A10=t[11]-fn*m1y*m2x, A11=t[12]-fn*m1y*m2y, A12=t[13]-fn*m1y*m2z;
        const float A20=t[14]-fn*m1z*m2x, A21=t[15]-fn*m1z*m2y, A22=t[16]-fn*m1z*m2z;

        const float det = A00*(A11*A22-A12*A21)
                        - A01*(A10*A22-A12*A20)
                        + A02*(A10*A21-A11*A20);

        // G = A^T A (symmetric PSD); analytic eigenvalues (fp32)
        const float G00 = A00*A00+A10*A10+A20*A20;
        const float G01 = A00*A01+A10*A11+A20*A21;
        const float G02 = A00*A02+A10*A12+A20*A22;
        const float G11 = A01*A01+A11*A11+A21*A21;
        const float G12 = A01*A02+A11*A12+A21*A22;
        const float G22 = A02*A02+A12*A12+A22*A22;

        const float q  = (G00+G11+G22)*(1.f/3.f);
        const float p1 = G01*G01 + G02*G02 + G12*G12;
        const float p2 = (G00-q)*(G00-q)+(G11-q)*(G11-q)+(G22-q)*(G22-q) + 2.f*p1;
        const float p  = sqrtf(p2*(1.f/6.f));
        float e1, e2, e3;
        if (p < 1e-20f) {
            e1 = e2 = e3 = q;
        } else {
            const float ip = 1.f/p;
            const float C00=(G00-q)*ip, C01=G01*ip, C02=G02*ip;
            const float C11=(G11-q)*ip, C12=G12*ip, C22=(G22-q)*ip;
            float detC = C00*(C11*C22-C12*C12)
                       - C01*(C01*C22-C12*C02)
                       + C02*(C01*C12-C11*C02);
            float rr = fminf(1.f, fmaxf(-1.f, 0.5f*detC));
            const float phi = acosf(rr)*(1.f/3.f);
            e1 = q + 2.f*p*cosf(phi);
            e3 = q + 2.f*p*cosf(phi + 2.0943951023931953f);  // +2*pi/3
            e2 = 3.f*q - e1 - e3;
        }
        const float sv0 = sqrtf(fmaxf(e1,0.f));
        const float sv1 = sqrtf(fmaxf(e2,0.f));
        const float sv2 = sqrtf(fmaxf(e3,0.f));
        const float trs = sv0 + sv1 + ((det >= 0.f) ? sv2 : -sv2);
        const float msd = fmaxf(0.f, (E0 - 2.f*trs)/fn);
        rms_out[b] = sqrtf(msd);
    }
}

__global__ __launch_bounds__(BLOCK) void mean_kernel(
    const float* __restrict__ rms, float* __restrict__ out, int B)
{
    const int tid = threadIdx.x;
    const float4* r4 = (const float4*)rms;
    float s = 0.f;
    for (int i = tid; i < B/4; i += BLOCK) {
        float4 v = r4[i];
        s += (v.x + v.y) + (v.z + v.w);
    }
    #pragma unroll
    for (int off = 32; off > 0; off >>= 1) s += __shfl_down(s, off, 64);
    __shared__ float sred[NWAVE];
    const int wave = tid >> 6, lane = tid & 63;
    if (lane == 0) sred[wave] = s;
    __syncthreads();
    if (tid == 0) {
        float tot = 0.f;
        #pragma unroll
        for (int w = 0; w < NWAVE; ++w) tot += sred[w];
        out[0] = tot / (float)B;
    }
}

extern "C" void kernel_launch(void* const* d_in, const int* in_sizes, int n_in,
                              void* d_out, int out_size, void* d_ws, size_t ws_size,
                              hipStream_t stream) {
    const float* yp = (const float*)d_in[0];   // y_prime [B,N,3] f32
    const float* yr = (const float*)d_in[1];   // y       [B,N,3] f32
    const int N = 2048;
    const int B = in_sizes[0] / (N * 3);
    float* rms_ws = (float*)d_ws;              // B floats

    rmsd_kernel<2048><<<B, BLOCK, 0, stream>>>(yp, yr, rms_ws);
    mean_kernel<<<1, BLOCK, 0, stream>>>(rms_ws, (float*)d_out, B);
}